// Round 1
// baseline (640.332 us; speedup 1.0000x reference)
//
#include <hip/hip_runtime.h>
#include <hip/hip_bf16.h>
#include <cstdint>

typedef __attribute__((ext_vector_type(8))) short s16x8;   // 8 bf16 = 4 VGPRs
typedef __attribute__((ext_vector_type(4))) float f32x4;   // MFMA C/D

union CV2 { __hip_bfloat162 h; uint32_t u; };

// ---------------------------------------------------------------------------
// Prep kernel: fold ln_w into W, ln_b + b into b', column sums S, and swizzle
// W' into MFMA B-fragment order as bf16.
//   Wb flat bf16 idx for (o,k): kk=k>>5, q=(k&31)>>3, j=k&7, t=o>>4, n=o&15,
//   lane l=q*16+n  ->  ((kk*4+t)*64 + l)*8 + j
// ---------------------------------------------------------------------------
__global__ void prep_kernel(const float* __restrict__ W,
                            const float* __restrict__ lnw,
                            const float* __restrict__ lnb,
                            const float* __restrict__ bias,
                            __hip_bfloat16* __restrict__ Wb,
                            float* __restrict__ Ssum,
                            float* __restrict__ bp) {
    const int o = blockIdx.x;      // 0..63
    const int tid = threadIdx.x;   // 0..255
    float s = 0.f, bb = 0.f;
    for (int k = tid; k < 768; k += 256) {
        float wraw = W[o * 768 + k];
        float wv = lnw[k] * wraw;
        s += wv;
        bb += lnb[k] * wraw;
        int kk = k >> 5, rem = k & 31;
        int q = rem >> 3, j = rem & 7;
        int t = o >> 4, n = o & 15;
        int l = q * 16 + n;
        Wb[(kk * 4 + t) * 512 + l * 8 + j] = __float2bfloat16(wv);
    }
    __shared__ float rs[4], rb[4];
    for (int off = 32; off > 0; off >>= 1) {
        s  += __shfl_down(s, off);
        bb += __shfl_down(bb, off);
    }
    int wid = tid >> 6;
    if ((tid & 63) == 0) { rs[wid] = s; rb[wid] = bb; }
    __syncthreads();
    if (tid == 0) {
        Ssum[o] = rs[0] + rs[1] + rs[2] + rs[3];
        bp[o]   = bias[o] + rb[0] + rb[1] + rb[2] + rb[3];
    }
}

// ---------------------------------------------------------------------------
// Fused LN + GEMM(768->64) + SiLU + unpatchify.
// Block = 256 thr (4 waves) handles one b (64 rows). Wave: 16 rows x 64 outs.
//   y[m,o] = rstd_m * (dot(x_m, W'_o) - mu_m * S_o) + b'_o ; silu ; permute.
// ---------------------------------------------------------------------------
__global__ __launch_bounds__(256, 4) void fused_kernel(
        const float* __restrict__ x,
        const uint4* __restrict__ Wb4,
        const float* __restrict__ Ssum,
        const float* __restrict__ bp,
        float* __restrict__ out) {
    const int b   = blockIdx.x;
    const int tid = threadIdx.x;
    const int w   = tid >> 6;   // wave 0..3
    const int l   = tid & 63;
    const int q   = l >> 4;     // quad 0..3
    const int n   = l & 15;

    // A-fragment row for this lane (m = lane&15); quad q covers k = q*8+j.
    const float* xrow = x + (size_t)(b * 64 + w * 16 + n) * 768 + q * 8;

    f32x4 acc0 = {0.f, 0.f, 0.f, 0.f};
    f32x4 acc1 = acc0, acc2 = acc0, acc3 = acc0;
    float sum = 0.f, ssq = 0.f;

    #pragma unroll
    for (int kk = 0; kk < 24; kk++) {
        float4 v0 = *(const float4*)(xrow + kk * 32);
        float4 v1 = *(const float4*)(xrow + kk * 32 + 4);
        sum += ((v0.x + v0.y) + (v0.z + v0.w)) + ((v1.x + v1.y) + (v1.z + v1.w));
        ssq = fmaf(v0.x, v0.x, ssq); ssq = fmaf(v0.y, v0.y, ssq);
        ssq = fmaf(v0.z, v0.z, ssq); ssq = fmaf(v0.w, v0.w, ssq);
        ssq = fmaf(v1.x, v1.x, ssq); ssq = fmaf(v1.y, v1.y, ssq);
        ssq = fmaf(v1.z, v1.z, ssq); ssq = fmaf(v1.w, v1.w, ssq);

        CV2 c0, c1, c2, c3;
        c0.h = __float22bfloat162_rn(make_float2(v0.x, v0.y));
        c1.h = __float22bfloat162_rn(make_float2(v0.z, v0.w));
        c2.h = __float22bfloat162_rn(make_float2(v1.x, v1.y));
        c3.h = __float22bfloat162_rn(make_float2(v1.z, v1.w));
        s16x8 a = __builtin_bit_cast(s16x8, make_uint4(c0.u, c1.u, c2.u, c3.u));

        const uint4* wp = Wb4 + kk * 256 + l;   // (kk*4+t)*64 + l
        s16x8 b0 = __builtin_bit_cast(s16x8, wp[0]);
        s16x8 b1 = __builtin_bit_cast(s16x8, wp[64]);
        s16x8 b2 = __builtin_bit_cast(s16x8, wp[128]);
        s16x8 b3 = __builtin_bit_cast(s16x8, wp[192]);

        acc0 = __builtin_amdgcn_mfma_f32_16x16x32_bf16(a, b0, acc0, 0, 0, 0);
        acc1 = __builtin_amdgcn_mfma_f32_16x16x32_bf16(a, b1, acc1, 0, 0, 0);
        acc2 = __builtin_amdgcn_mfma_f32_16x16x32_bf16(a, b2, acc2, 0, 0, 0);
        acc3 = __builtin_amdgcn_mfma_f32_16x16x32_bf16(a, b3, acc3, 0, 0, 0);
    }

    // Row stats: reduce across the 4 lanes sharing m (xor 16, xor 32).
    sum += __shfl_xor(sum, 16); sum += __shfl_xor(sum, 32);
    ssq += __shfl_xor(ssq, 16); ssq += __shfl_xor(ssq, 32);
    const float mu   = sum * (1.0f / 768.0f);
    const float var  = ssq * (1.0f / 768.0f) - mu * mu;
    const float rstd = rsqrtf(var + 1e-5f);

    float St[4], Bt[4];
    #pragma unroll
    for (int t = 0; t < 4; t++) {
        St[t] = Ssum[t * 16 + n];   // o = 16t + n
        Bt[t] = bp[t * 16 + n];
    }

    __shared__ float sout[4096];   // one b's output, unpatchified order
    const int o2 = (n >> 2) & 3;
    const int o3 = n & 3;
    #pragma unroll
    for (int r = 0; r < 4; r++) {
        // D layout: this lane holds rows m = q*4+r, col n. Stats live on lane m.
        float mu_r   = __shfl(mu,   q * 4 + r);
        float rstd_r = __shfl(rstd, q * 4 + r);
        int cc  = w * 16 + q * 4 + r;
        int c1i = cc >> 3, c2i = cc & 7;
        int base = (c1i * 4 + o2) * 32 + c2i * 4 + o3;
        float v[4] = {acc0[r], acc1[r], acc2[r], acc3[r]};
        #pragma unroll
        for (int t = 0; t < 4; t++) {
            float y = rstd_r * (v[t] - mu_r * St[t]) + Bt[t];
            y = y / (1.0f + __expf(-y));           // SiLU
            sout[t * 1024 + base] = y;             // out[b][t][c1*4+o2][c2*4+o3]
        }
    }
    __syncthreads();

    float* outp = out + (size_t)b * 4096;
    #pragma unroll
    for (int j = 0; j < 4; j++) {
        *(float4*)(outp + j * 1024 + tid * 4) =
            *(const float4*)(&sout[j * 1024 + tid * 4]);
    }
}

extern "C" void kernel_launch(void* const* d_in, const int* in_sizes, int n_in,
                              void* d_out, int out_size, void* d_ws, size_t ws_size,
                              hipStream_t stream) {
    const float* x    = (const float*)d_in[0];
    const float* lnw  = (const float*)d_in[1];
    const float* lnb  = (const float*)d_in[2];
    const float* W    = (const float*)d_in[3];
    const float* bias = (const float*)d_in[4];
    float* out = (float*)d_out;

    const int B = in_sizes[0] / (64 * 768);   // 2048

    __hip_bfloat16* Wb = (__hip_bfloat16*)d_ws;                 // 98304 B
    float* Ssum = (float*)((char*)d_ws + 98304);                // 256 B
    float* bp   = (float*)((char*)d_ws + 98304 + 256);          // 256 B

    prep_kernel<<<64, 256, 0, stream>>>(W, lnw, lnb, bias, Wb, Ssum, bp);
    fused_kernel<<<B, 256, 0, stream>>>(x, (const uint4*)d_ws, Ssum, bp, out);
}